// Round 4
// baseline (231.604 us; speedup 1.0000x reference)
//
#include <hip/hip_runtime.h>
#include <hip/hip_bf16.h>

typedef __attribute__((ext_vector_type(8))) short short8;
typedef __attribute__((ext_vector_type(4))) float floatx4;

#define MARGIN 0.3f
static constexpr int N = 8192;   // b*n points
static constexpr int C = 256;    // feature dim

// ---- workspace layout (bytes) ----
static constexpr size_t OFF_SQ    = 4194304;           // after fb (4 MB)
static constexpr size_t OFF_PMX   = 4227072;
static constexpr size_t OFF_NMN   = 4259840;
static constexpr size_t OFF_SCL   = 4292608;  // [0] small total, [1] trip acc, [2](u32) donecnt, [8..71] small partials
static constexpr size_t OFF_CPART = 4293120;  // float[2][64][8192] = 4 MB (sym only)
static constexpr size_t OFF_CPOS  = 8487424;  // float[64][8192]    = 2 MB (sym only)
static constexpr size_t NEED_SYM  = 10584576;

// async 16B global->LDS (dest = wave-uniform base + lane*16)
__device__ __forceinline__ void async16(const void* g, void* l) {
    __builtin_amdgcn_global_load_lds(
        (const __attribute__((address_space(1))) unsigned int*)g,
        (__attribute__((address_space(3))) unsigned int*)l, 16, 0, 0);
}

// ---------------- kernel 0: convert+norms+init (blocks 0..2047) fused with
// ---------------- mse/dr partial sums (blocks 2048..2111) ----------------------
__global__ void k_prep(const float* __restrict__ feat,
                       const float* __restrict__ s0, const float* __restrict__ s1,
                       const float* __restrict__ s2, const float* __restrict__ g,
                       const float* __restrict__ e0, const float* __restrict__ e1,
                       const float* __restrict__ l0, const float* __restrict__ l1,
                       __hip_bfloat16* __restrict__ fb, float* __restrict__ sq,
                       unsigned* __restrict__ posmax, unsigned* __restrict__ negmin,
                       float* __restrict__ scl) {
    int bid = blockIdx.x, tid = threadIdx.x;
    if (bid < 2048) {
        int row = bid * 4 + (tid >> 6);
        int lane = tid & 63;
        float4 v = ((const float4*)feat)[row * 64 + lane];
        union { __hip_bfloat16 h[4]; ushort4 u; } cv;
        cv.h[0] = __float2bfloat16(v.x); cv.h[1] = __float2bfloat16(v.y);
        cv.h[2] = __float2bfloat16(v.z); cv.h[3] = __float2bfloat16(v.w);
        ((ushort4*)fb)[row * 64 + lane] = cv.u;
        float s = v.x * v.x + v.y * v.y + v.z * v.z + v.w * v.w;
#pragma unroll
        for (int off = 32; off; off >>= 1) s += __shfl_xor(s, off);
        if (lane == 0) {
            sq[row] = s;
            posmax[row] = 0u;
            negmin[row] = 0x7f800000u;   // +inf
        }
    } else {
        int sb = bid - 2048;
        if (sb == 0 && tid == 0) { scl[1] = 0.f; ((unsigned*)scl)[2] = 0u; }
        const int E = 64 * 1024;
        int t = sb * 256 + tid, nth = 64 * 256;
        float acc = 0.f;
        for (int i = t; i < E; i += nth) acc += fabsf(e0[i] - l0[i]) * (1.f / E);
        for (int i = t; i < E; i += nth) acc += fabsf(e1[i] - l1[i]) * (1.f / E);
        if (t < 192) {
            int k = t >> 6, i = t & 63;
            const float* s = (k == 0) ? s0 : ((k == 1) ? s1 : s2);
            float d = s[i] - g[i];
            acc += d * d * (1.f / 192.f);
        }
#pragma unroll
        for (int off = 32; off; off >>= 1) acc += __shfl_xor(acc, off);
        __shared__ float red[4];
        if ((tid & 63) == 0) red[tid >> 6] = acc;
        __syncthreads();
        if (tid == 0) scl[8 + sb] = red[0] + red[1] + red[2] + red[3];
    }
}

// ---------------- kernel 1: symmetric pairwise mining, no in-loop atomics ------
// Flat upper-triangle tile list (i<=j), G=4 tiles/block. Row side: registers,
// flushed via end atomics. Mirror side (i<j): per-tile column-min / diag-pos
// written by unique owners to colpart/colpos (plain stores). Labels have
// period 128 => same-label pairs inside any 128-tile are its local diagonal.
__global__ __launch_bounds__(256, 2)
void k_trip(const __hip_bfloat16* __restrict__ fb, const float* __restrict__ sq,
            unsigned* __restrict__ posmax, unsigned* __restrict__ negmin,
            float* __restrict__ colpart, float* __restrict__ colpos,
            float* __restrict__ scl, int sym, int ntile) {
    __shared__ uint4 Bs[4096];   // 128 rows x 32 granules = 64 KB (full K=256)

    const int t = threadIdx.x;
    const int w = t >> 6, lane = t & 63;
    const int wi = w >> 1, wj = w & 1;
    const int quad = lane >> 4, l15 = lane & 15;

    // block 0, wave 0: combine the 64 small partials from k_prep
    if (blockIdx.x == 0 && w == 0) {
        float v = scl[8 + lane];
#pragma unroll
        for (int off = 32; off; off >>= 1) v += __shfl_xor(v, off);
        if (lane == 0) scl[0] = v;
    }

    short8 a[4][8];
    float si[16], nm[16], pm[4];
    int curi = -1;

    auto flush = [&](int ci) {
#pragma unroll
        for (int q = 0; q < 16; ++q) {
            float v = nm[q];
#pragma unroll
            for (int off = 1; off < 16; off <<= 1) v = fminf(v, __shfl_xor(v, off));
            if (l15 == 0) {
                int row = ci * 128 + wi * 64 + (q >> 2) * 16 + quad * 4 + (q & 3);
                atomicMin(&negmin[row], __float_as_uint(fmaxf(v + si[q], 0.f)));
            }
        }
        if (wi == wj && (l15 >> 2) == quad) {
#pragma unroll
            for (int ti = 0; ti < 4; ++ti) {
                int row = ci * 128 + wi * 64 + ti * 16 + l15;
                atomicMax(&posmax[row],
                          __float_as_uint(fmaxf(pm[ti] + si[ti * 4 + (l15 & 3)], 0.f)));
            }
        }
    };

#pragma unroll 1
    for (int gidx = 0; gidx < 4; ++gidx) {
        int tile = blockIdx.x * 4 + gidx;
        if (tile >= ntile) break;
        int i, j;
        if (sym) {   // upper triangle, row-major: row i has 64-i tiles
            int ii = 0, off = 0;
            while (off + (64 - ii) <= tile) { off += 64 - ii; ++ii; }
            i = ii; j = ii + (tile - off);
        } else {
            i = tile >> 6; j = tile & 63;
        }
        const int ib = i * 128, jb = j * 128;
        const bool mirror = sym && (i < j);

        if (i != curi) {
            if (curi >= 0) flush(curi);
#pragma unroll
            for (int ti = 0; ti < 4; ++ti) {
                const __hip_bfloat16* ap =
                    fb + (size_t)(ib + wi * 64 + ti * 16 + l15) * C + quad * 8;
#pragma unroll
                for (int k = 0; k < 8; ++k) a[ti][k] = *(const short8*)(ap + k * 32);
            }
#pragma unroll
            for (int q = 0; q < 16; ++q) {
                si[q] = sq[ib + wi * 64 + (q >> 2) * 16 + quad * 4 + (q & 3)];
                nm[q] = INFINITY;
            }
#pragma unroll
            for (int q = 0; q < 4; ++q) pm[q] = -INFINITY;
            curi = i;
        }

        __syncthreads();                       // prior tile's LDS reads done
        // stage B tile (128 rows x K=256 = 64 KB), XOR-swizzled at the source:
        // LDS slot s holds granule (s&31) ^ (srow&7) of row srow = s>>5.
#pragma unroll
        for (int st = 0; st < 16; ++st) {
            int s = st * 256 + t;
            int srow = s >> 5, sg = s & 31;
            int gg = sg ^ (srow & 7);
            async16(fb + (size_t)(jb + srow) * C + gg * 8, &Bs[st * 256 + (t & ~63)]);
        }
        __syncthreads();                       // staging complete

        float cm[4], sjv[4];
#pragma unroll
        for (int q = 0; q < 4; ++q) cm[q] = INFINITY;

#pragma unroll
        for (int tjh = 0; tjh < 2; ++tjh) {    // two half-j passes (acc = 32 regs)
            floatx4 acc[4][2];
#pragma unroll
            for (int ti = 0; ti < 4; ++ti)
#pragma unroll
                for (int tjj = 0; tjj < 2; ++tjj)
                    acc[ti][tjj] = (floatx4){0.f, 0.f, 0.f, 0.f};

#pragma unroll
            for (int k = 0; k < 8; ++k) {
                short8 b[2];
#pragma unroll
                for (int tjj = 0; tjj < 2; ++tjj) {
                    int col = wj * 64 + (tjh * 2 + tjj) * 16 + l15;
                    int gg = k * 4 + quad;
                    b[tjj] = *(const short8*)&Bs[col * 32 + (gg ^ (col & 7))];
                }
#pragma unroll
                for (int ti = 0; ti < 4; ++ti)
#pragma unroll
                    for (int tjj = 0; tjj < 2; ++tjj)
                        acc[ti][tjj] = __builtin_amdgcn_mfma_f32_16x16x32_bf16(
                            a[ti][k], b[tjj], acc[ti][tjj], 0, 0, 0);
            }

            // mining epilogue
#pragma unroll
            for (int tjj = 0; tjj < 2; ++tjj) {
                int tj = tjh * 2 + tjj, q = tjh * 2 + tjj;
                int jjl = wj * 64 + tj * 16 + l15;      // local col 0..127
                float sj = sq[jb + jjl];
                sjv[q] = sj;
#pragma unroll
                for (int ti = 0; ti < 4; ++ti) {
                    bool diag_tile = (wi == wj) && (ti == tj);
#pragma unroll
                    for (int r = 0; r < 4; ++r) {
                        float dot = acc[ti][tjj][r];
                        float vr = fmaf(-2.f, dot, sj);
                        bool isd = diag_tile && (l15 == quad * 4 + r);  // same label
                        nm[ti * 4 + r] = fminf(nm[ti * 4 + r], isd ? INFINITY : vr);
                        if (isd && i != j) {
                            pm[ti] = fmaxf(pm[ti], vr);   // row-side positive
                            if (mirror)                    // unique owner store
                                colpos[i * N + jb + jjl] =
                                    fmaxf(vr + si[ti * 4 + r], 0.f);
                        }
                        if (mirror) {
                            float vc = fmaf(-2.f, dot, si[ti * 4 + r]);
                            cm[q] = fminf(cm[q], isd ? INFINITY : vc);
                        }
                    }
                }
            }
        }

        if (mirror) {
            // reduce col-mins over the 4 quads (rows), then coalesced store:
            // lane (quad,l15) stores column quad*16+l15 of its wj half, plane wi.
#pragma unroll
            for (int q = 0; q < 4; ++q) {
                cm[q] = fminf(cm[q], __shfl_xor(cm[q], 16));
                cm[q] = fminf(cm[q], __shfl_xor(cm[q], 32));
            }
            float v = (quad == 0) ? cm[0] : (quad == 1) ? cm[1] : (quad == 2) ? cm[2] : cm[3];
            float s = (quad == 0) ? sjv[0] : (quad == 1) ? sjv[1] : (quad == 2) ? sjv[2] : sjv[3];
            int col = jb + wj * 64 + quad * 16 + l15;
            colpart[(size_t)wi * 64 * N + (size_t)i * N + col] = fmaxf(v + s, 0.f);
        }
    }
    if (curi >= 0) flush(curi);
}

// ---------------- kernel 2: fold partials + final combine ----------------------
__global__ void k_final(const unsigned* __restrict__ posmax, const unsigned* __restrict__ negmin,
                        const float* __restrict__ colpart, const float* __restrict__ colpos,
                        float* __restrict__ scl, float* __restrict__ out, int sym) {
    int r = blockIdx.x * 256 + threadIdx.x;
    float v = __uint_as_float(negmin[r]);
    float p = __uint_as_float(posmax[r]);
    if (sym) {
        int T = r >> 7;
        for (int i = 0; i < T; ++i) {
            v = fminf(v, colpart[i * N + r]);
            v = fminf(v, colpart[64 * N + i * N + r]);
            p = fmaxf(p, colpos[i * N + r]);
        }
    }
    float acc = fmaxf(sqrtf(p) - sqrtf(v) + MARGIN, 0.f);
#pragma unroll
    for (int off = 32; off; off >>= 1) acc += __shfl_xor(acc, off);
    __shared__ float red[4];
    if ((threadIdx.x & 63) == 0) red[threadIdx.x >> 6] = acc;
    __syncthreads();
    if (threadIdx.x == 0) {
        atomicAdd(&scl[1], red[0] + red[1] + red[2] + red[3]);
        __threadfence();
        unsigned old = atomicAdd((unsigned*)scl + 2, 1u);
        if (old == 31) {   // last block: everything else has landed
            float trip = atomicAdd(&scl[1], 0.f);   // coherent read
            out[0] = scl[0] + trip * (1.f / N);
        }
    }
}

extern "C" void kernel_launch(void* const* d_in, const int* in_sizes, int n_in,
                              void* d_out, int out_size, void* d_ws, size_t ws_size,
                              hipStream_t stream) {
    const float* feat = (const float*)d_in[0];
    const float* gt   = (const float*)d_in[1];
    const float* s0   = (const float*)d_in[2];
    const float* s1   = (const float*)d_in[3];
    const float* s2   = (const float*)d_in[4];
    const float* e0   = (const float*)d_in[5];
    const float* e1   = (const float*)d_in[6];
    const float* l0   = (const float*)d_in[7];
    const float* l1   = (const float*)d_in[8];
    float* out = (float*)d_out;

    char* ws = (char*)d_ws;
    __hip_bfloat16* fb = (__hip_bfloat16*)ws;
    float*    sq      = (float*)(ws + OFF_SQ);
    unsigned* posmax  = (unsigned*)(ws + OFF_PMX);
    unsigned* negmin  = (unsigned*)(ws + OFF_NMN);
    float*    scl     = (float*)(ws + OFF_SCL);
    float*    colpart = (float*)(ws + OFF_CPART);
    float*    colpos  = (float*)(ws + OFF_CPOS);

    const int sym = (ws_size >= NEED_SYM) ? 1 : 0;
    const int ntile = sym ? 2080 : 4096;
    const int nblk = ntile / 4;

    k_prep<<<2112, 256, 0, stream>>>(feat, s0, s1, s2, gt, e0, e1, l0, l1,
                                     fb, sq, posmax, negmin, scl);
    k_trip<<<nblk, 256, 0, stream>>>(fb, sq, posmax, negmin, colpart, colpos,
                                     scl, sym, ntile);
    k_final<<<32, 256, 0, stream>>>(posmax, negmin, colpart, colpos, scl, out, sym);
}

// Round 7
// 171.662 us; speedup vs baseline: 1.3492x; 1.3492x over previous
//
#include <hip/hip_runtime.h>
#include <hip/hip_bf16.h>

typedef __attribute__((ext_vector_type(8))) short short8;
typedef __attribute__((ext_vector_type(4))) float floatx4;

#define MARGIN 0.3f
static constexpr int N = 8192;   // b*n points
static constexpr int C = 256;    // feature dim

// async 16B global->LDS (dest = wave-uniform base + lane*16)
__device__ __forceinline__ void async16(const void* g, void* l) {
    __builtin_amdgcn_global_load_lds(
        (const __attribute__((address_space(1))) unsigned int*)g,
        (__attribute__((address_space(3))) unsigned int*)l, 16, 0, 0);
}

// ---------------- kernel 0: convert+norms+init (blocks 0..2047) fused with
// ---------------- mse/dr partial sums (blocks 2048..2111) ----------------------
__global__ void k_prep(const float* __restrict__ feat,
                       const float* __restrict__ s0, const float* __restrict__ s1,
                       const float* __restrict__ s2, const float* __restrict__ g,
                       const float* __restrict__ e0, const float* __restrict__ e1,
                       const float* __restrict__ l0, const float* __restrict__ l1,
                       __hip_bfloat16* __restrict__ fb, float* __restrict__ sq,
                       unsigned* __restrict__ posmax, unsigned* __restrict__ negmin,
                       float* __restrict__ smallpart, unsigned* __restrict__ donecnt) {
    int bid = blockIdx.x, tid = threadIdx.x;
    if (bid < 2048) {
        int row = bid * 4 + (tid >> 6);
        int lane = tid & 63;
        float4 v = ((const float4*)feat)[row * 64 + lane];
        union { __hip_bfloat16 h[4]; ushort4 u; } cv;
        cv.h[0] = __float2bfloat16(v.x); cv.h[1] = __float2bfloat16(v.y);
        cv.h[2] = __float2bfloat16(v.z); cv.h[3] = __float2bfloat16(v.w);
        ((ushort4*)fb)[row * 64 + lane] = cv.u;
        float s = v.x * v.x + v.y * v.y + v.z * v.z + v.w * v.w;
#pragma unroll
        for (int off = 32; off; off >>= 1) s += __shfl_xor(s, off);
        if (lane == 0) {
            sq[row] = s;
            posmax[row] = 0u;
            negmin[row] = 0x7f800000u;   // +inf
        }
    } else {
        int sb = bid - 2048;
        if (sb == 0 && tid == 0) *donecnt = 0u;
        const int E = 64 * 1024;
        int t = sb * 256 + tid, nth = 64 * 256;
        float acc = 0.f;
        for (int i = t; i < E; i += nth) acc += fabsf(e0[i] - l0[i]) * (1.f / E);
        for (int i = t; i < E; i += nth) acc += fabsf(e1[i] - l1[i]) * (1.f / E);
        if (t < 192) {
            int k = t >> 6, i = t & 63;
            const float* s = (k == 0) ? s0 : ((k == 1) ? s1 : s2);
            float d = s[i] - g[i];
            acc += d * d * (1.f / 192.f);
        }
#pragma unroll
        for (int off = 32; off; off >>= 1) acc += __shfl_xor(acc, off);
        __shared__ float red[4];
        if ((tid & 63) == 0) red[tid >> 6] = acc;
        __syncthreads();
        if (tid == 0) smallpart[sb] = red[0] + red[1] + red[2] + red[3];
    }
}

// ---------------- kernel 1: pairwise mining, pipelined, fused finish -----------
// 512 blocks (2/CU): i-tile = blk>>3, 8 j-tiles = (blk&7)*8 ... +7.
// A tile (128 x K=256) in registers. B staged per half-K (32 KiB) into a
// double buffer via global_load_lds, one chunk ahead, so each barrier's
// vmcnt(0) drain finds loads issued a full compute phase earlier.
// Last block (donecount) folds negmin/posmax + smallpart -> out.
__global__ __launch_bounds__(256, 2)
void k_trip(const __hip_bfloat16* __restrict__ fb, const float* __restrict__ sq,
            unsigned* __restrict__ posmax, unsigned* __restrict__ negmin,
            const float* __restrict__ smallpart, unsigned* __restrict__ donecnt,
            float* __restrict__ out) {
    __shared__ uint4 Bs[2][2048];         // two 32 KiB half-K buffers = 64 KiB exact

    const int tid = threadIdx.x, blk = blockIdx.x;
    const int w = tid >> 6, lane = tid & 63;
    const int wi = w >> 1, wj = w & 1;
    const int quad = lane >> 4, l15 = lane & 15;

    const int i = blk >> 3;
    const int jgrp = blk & 7;
    const int ib = i * 128;

    // ---- A tile in registers (rows wi*64 + ti*16 + l15, all K=256) ----
    short8 a[4][8];
#pragma unroll
    for (int ti = 0; ti < 4; ++ti) {
        const __hip_bfloat16* ap =
            fb + (size_t)(ib + wi * 64 + ti * 16 + l15) * C + quad * 8;
#pragma unroll
        for (int k = 0; k < 8; ++k) a[ti][k] = *(const short8*)(ap + k * 32);
    }

    float nm[16], pm[4];
#pragma unroll
    for (int q = 0; q < 16; ++q) nm[q] = INFINITY;
#pragma unroll
    for (int q = 0; q < 4; ++q) pm[q] = -INFINITY;

    // stage chunk s (tile s>>1, K-half s&1) into Bs[s&1], XOR-swizzled at source:
    // slot = col*16 + (g ^ (col&7)); dest is wave-uniform base + lane*16.
    auto stage = [&](int s) {
        int jt = s >> 1, kc = s & 1;
        const __hip_bfloat16* src =
            fb + (size_t)(jgrp * 8 + jt) * 128 * C + kc * 128;
        uint4* buf = Bs[kc];
#pragma unroll
        for (int st = 0; st < 8; ++st) {
            int slot = st * 256 + w * 64 + lane;
            int col = slot >> 4, gs = slot & 15;
            int g = gs ^ (col & 7);
            async16(src + (size_t)col * C + g * 8, &buf[st * 256 + w * 64]);
        }
    };

    floatx4 acc[4][4];

    stage(0);
    __syncthreads();                       // chunk 0 resident

#pragma unroll 1
    for (int jt = 0; jt < 8; ++jt) {
        const int j = jgrp * 8 + jt;
        const int jb = j * 128;

        stage(2 * jt + 1);                 // this tile's K-half 1 -> Bs[1]

        float sjv[4];
#pragma unroll
        for (int tj = 0; tj < 4; ++tj) sjv[tj] = sq[jb + wj * 64 + tj * 16 + l15];

#pragma unroll
        for (int ti = 0; ti < 4; ++ti)
#pragma unroll
            for (int tj = 0; tj < 4; ++tj)
                acc[ti][tj] = (floatx4){0.f, 0.f, 0.f, 0.f};

        {   // K-half 0 on Bs[0]
            const uint4* buf = Bs[0];
#pragma unroll
            for (int k2 = 0; k2 < 4; ++k2) {
                short8 bf[4];
                int g = k2 * 4 + quad;
#pragma unroll
                for (int tj = 0; tj < 4; ++tj) {
                    int col = wj * 64 + tj * 16 + l15;
                    bf[tj] = *(const short8*)&buf[col * 16 + (g ^ (col & 7))];
                }
#pragma unroll
                for (int ti = 0; ti < 4; ++ti)
#pragma unroll
                    for (int tj = 0; tj < 4; ++tj)
                        acc[ti][tj] = __builtin_amdgcn_mfma_f32_16x16x32_bf16(
                            a[ti][k2], bf[tj], acc[ti][tj], 0, 0, 0);
            }
        }
        __syncthreads();                   // Bs[0] readers done; Bs[1] resident
        if (jt < 7) stage(2 * jt + 2);     // next tile's K-half 0 -> Bs[0]
        {   // K-half 1 on Bs[1]
            const uint4* buf = Bs[1];
#pragma unroll
            for (int k2 = 0; k2 < 4; ++k2) {
                short8 bf[4];
                int g = k2 * 4 + quad;
#pragma unroll
                for (int tj = 0; tj < 4; ++tj) {
                    int col = wj * 64 + tj * 16 + l15;
                    bf[tj] = *(const short8*)&buf[col * 16 + (g ^ (col & 7))];
                }
#pragma unroll
                for (int ti = 0; ti < 4; ++ti)
#pragma unroll
                    for (int tj = 0; tj < 4; ++tj)
                        acc[ti][tj] = __builtin_amdgcn_mfma_f32_16x16x32_bf16(
                            a[ti][4 + k2], bf[tj], acc[ti][tj], 0, 0, 0);
            }
        }

        // epilogue: diag waves extract positives then poison diag; branch-free min
        if (wi == wj) {
#pragma unroll
            for (int ti = 0; ti < 4; ++ti) {
#pragma unroll
                for (int r = 0; r < 4; ++r) {
                    if (l15 == quad * 4 + r) {       // lane owning the diag element
                        if (j != i)
                            pm[ti] = fmaxf(pm[ti], fmaf(-2.f, acc[ti][ti][r], sjv[ti]));
                        acc[ti][ti][r] = -1e30f;     // vr -> +2e30: excluded from min
                    }
                }
            }
        }
#pragma unroll
        for (int tj = 0; tj < 4; ++tj)
#pragma unroll
            for (int ti = 0; ti < 4; ++ti)
#pragma unroll
                for (int r = 0; r < 4; ++r)
                    nm[ti * 4 + r] = fminf(nm[ti * 4 + r],
                                           fmaf(-2.f, acc[ti][tj][r], sjv[tj]));

        __syncthreads();                   // Bs[1] readers done before next overwrite
    }

    // ---- flush row-side mining state ----
#pragma unroll
    for (int q = 0; q < 16; ++q) {
        float v = nm[q];
#pragma unroll
        for (int off = 1; off < 16; off <<= 1) v = fminf(v, __shfl_xor(v, off));
        if (l15 == 0) {
            int row = ib + wi * 64 + (q >> 2) * 16 + quad * 4 + (q & 3);
            atomicMin(&negmin[row], __float_as_uint(fmaxf(v + sq[row], 0.f)));
        }
    }
    if (wi == wj && (l15 >> 2) == quad) {
#pragma unroll
        for (int ti = 0; ti < 4; ++ti) {
            int row = ib + wi * 64 + ti * 16 + l15;
            atomicMax(&posmax[row], __float_as_uint(fmaxf(pm[ti] + sq[row], 0.f)));
        }
    }

    // ---- donecount: last block folds everything -> out ----
    __threadfence();                       // flush atomics visible device-wide
    __syncthreads();                       // all threads' flushes issued
    int* lastflag = (int*)&Bs[0][0];       // LDS reuse: no pending Bs readers
    if (tid == 0) {
        unsigned old = atomicAdd(donecnt, 1u);
        lastflag[0] = (old == 511u) ? 1 : 0;
    }
    __syncthreads();
    if (lastflag[0]) {
        float acc2 = 0.f;
        for (int r = tid; r < N; r += 256) {
            unsigned pu = __hip_atomic_load(&posmax[r], __ATOMIC_RELAXED,
                                            __HIP_MEMORY_SCOPE_AGENT);
            unsigned vu = __hip_atomic_load(&negmin[r], __ATOMIC_RELAXED,
                                            __HIP_MEMORY_SCOPE_AGENT);
            acc2 += fmaxf(sqrtf(__uint_as_float(pu)) - sqrtf(__uint_as_float(vu))
                          + MARGIN, 0.f);
        }
        acc2 *= (1.f / N);
        if (tid < 64) acc2 += smallpart[tid];
#pragma unroll
        for (int off = 32; off; off >>= 1) acc2 += __shfl_xor(acc2, off);
        float* red = (float*)&Bs[1][0];
        if (lane == 0) red[w] = acc2;
        __syncthreads();
        if (tid == 0) out[0] = red[0] + red[1] + red[2] + red[3];
    }
}

extern "C" void kernel_launch(void* const* d_in, const int* in_sizes, int n_in,
                              void* d_out, int out_size, void* d_ws, size_t ws_size,
                              hipStream_t stream) {
    const float* feat = (const float*)d_in[0];
    const float* gt   = (const float*)d_in[1];
    const float* s0   = (const float*)d_in[2];
    const float* s1   = (const float*)d_in[3];
    const float* s2   = (const float*)d_in[4];
    const float* e0   = (const float*)d_in[5];
    const float* e1   = (const float*)d_in[6];
    const float* l0   = (const float*)d_in[7];
    const float* l1   = (const float*)d_in[8];
    float* out = (float*)d_out;

    char* ws = (char*)d_ws;
    __hip_bfloat16* fb = (__hip_bfloat16*)ws;                         // 4 MB
    float*    sq        = (float*)(ws + (size_t)N * C * 2);           // 32 KB
    unsigned* posmax    = (unsigned*)(ws + (size_t)N * C * 2 + N * 4);
    unsigned* negmin    = (unsigned*)(ws + (size_t)N * C * 2 + N * 8);
    float*    smallpart = (float*)(ws + (size_t)N * C * 2 + N * 12);
    unsigned* donecnt   = (unsigned*)(ws + (size_t)N * C * 2 + N * 12 + 1024);

    k_prep<<<2112, 256, 0, stream>>>(feat, s0, s1, s2, gt, e0, e1, l0, l1,
                                     fb, sq, posmax, negmin, smallpart, donecnt);
    k_trip<<<512, 256, 0, stream>>>(fb, sq, posmax, negmin, smallpart, donecnt, out);
}